// Round 4
// baseline (26.611 us; speedup 1.0000x reference)
//
#include <hip/hip_runtime.h>

// BSpline3D: out[b,c,d,h,w] = sum_k relu(x[b,c,d,h,w] - knots[k])^3 * weights[c,k]
// x: (2, 32, 64, 64, 64) f32, knots: (10,) f32, weights: (32, 10) f32.
// Memory-bound streaming op: 64 MiB in + 64 MiB out.
// Round 4: batch-4 load pipeline (4 float4 reads in flight per wave),
// non-temporal stores via clang ext_vector_type (HIP float4 is a class and
// rejected by __builtin_nontemporal_store), VGPR capped via launch_bounds.

#define NK 10
#define VECS_PER_CHUNK 65536   // 64^3 / 4 float4s per (b,c) chunk
#define BLOCKS_PER_CHUNK 32
#define VECS_PER_BLOCK 2048    // VECS_PER_CHUNK / BLOCKS_PER_CHUNK
#define BATCH 4
#define OUTER 2                // VECS_PER_BLOCK / (BATCH * 256)

typedef float vfloat4 __attribute__((ext_vector_type(4)));

__global__ __launch_bounds__(256, 8) void bspline3d_kernel(
    const float* __restrict__ x,
    const float* __restrict__ knots,
    const float* __restrict__ weights,
    float* __restrict__ out)
{
    const int blk   = blockIdx.x;
    const int chunk = blk >> 5;        // 0..63 : linear (b, c) chunk index
    const int sub   = blk & 31;        // 0..31 : sub-block within the chunk
    const int c     = chunk & 31;      // channel — uniform across the block

    // Block-uniform: compiler scalarizes these into SGPRs.
    float kn[NK], w[NK];
    const float* __restrict__ wc = weights + c * NK;
#pragma unroll
    for (int k = 0; k < NK; ++k) { kn[k] = knots[k]; w[k] = wc[k]; }

    const long base = (long)chunk * VECS_PER_CHUNK + (long)sub * VECS_PER_BLOCK;
    const vfloat4* __restrict__ xv4 = reinterpret_cast<const vfloat4*>(x) + base;
    vfloat4* __restrict__ ov4       = reinterpret_cast<vfloat4*>(out) + base;

    const int tid = (int)threadIdx.x;

#pragma unroll
    for (int i = 0; i < OUTER; ++i) {
        // Issue all BATCH loads before any compute: 4 dwordx4 in flight.
        vfloat4 xv[BATCH];
#pragma unroll
        for (int j = 0; j < BATCH; ++j)
            xv[j] = xv4[i * (BATCH * 256) + j * 256 + tid];

#pragma unroll
        for (int j = 0; j < BATCH; ++j) {
            vfloat4 acc = (vfloat4)(0.f);
#pragma unroll
            for (int k = 0; k < NK; ++k) {
                const float kk = kn[k];
                const float wk = w[k];
                vfloat4 b;
                b.x = fmaxf(xv[j].x - kk, 0.f);
                b.y = fmaxf(xv[j].y - kk, 0.f);
                b.z = fmaxf(xv[j].z - kk, 0.f);
                b.w = fmaxf(xv[j].w - kk, 0.f);
                acc.x = fmaf((b.x * b.x) * b.x, wk, acc.x);
                acc.y = fmaf((b.y * b.y) * b.y, wk, acc.y);
                acc.z = fmaf((b.z * b.z) * b.z, wk, acc.z);
                acc.w = fmaf((b.w * b.w) * b.w, wk, acc.w);
            }
            // Output is never re-read: bypass cache allocation.
            __builtin_nontemporal_store(acc, &ov4[i * (BATCH * 256) + j * 256 + tid]);
        }
    }
}

extern "C" void kernel_launch(void* const* d_in, const int* in_sizes, int n_in,
                              void* d_out, int out_size, void* d_ws, size_t ws_size,
                              hipStream_t stream) {
    const float* x       = (const float*)d_in[0];
    const float* knots   = (const float*)d_in[1];
    const float* weights = (const float*)d_in[2];
    float* out           = (float*)d_out;

    // out_size = 2*32*64^3 = 16,777,216 floats -> 64 chunks of 65536 float4s.
    const int nchunks = (out_size / 4) / VECS_PER_CHUNK;   // 64
    const int grid = nchunks * BLOCKS_PER_CHUNK;           // 2048

    bspline3d_kernel<<<grid, 256, 0, stream>>>(x, knots, weights, out);
}